// Round 8
// baseline (830.695 us; speedup 1.0000x reference)
//
#include <hip/hip_runtime.h>
#include <hip/hip_bf16.h>

#define NN 100000
#define NROWS_PAD 100032
#define EE 1600000
#define GG 512
#define NPB 256                                            // nodes per bucket
#define NB  ((NN + NPB - 1) / NPB)                         // 391 buckets
#define PCHUNK 4096                                        // edges per partition block
#define PBLOCKS ((EE + PCHUNK - 1) / PCHUNK)               // 391
static constexpr float BN_EPS = 1e-5f;

typedef _Float16 half8 __attribute__((ext_vector_type(8)));
typedef float floatx4 __attribute__((ext_vector_type(4)));

// ---------------------------------------------------------------------------
// CSR build (write-local). ebuf packed: src (bits 0-16) | (dst&255) << 17
// ---------------------------------------------------------------------------

__global__ __launch_bounds__(256) void k_bhist(const int* __restrict__ EI,
                                               int* __restrict__ bcount)
{
    __shared__ int h[NB];
    const int t = threadIdx.x;
    for (int i = t; i < NB; i += 256) h[i] = 0;
    __syncthreads();
    const int e0 = blockIdx.x * PCHUNK;
    const int e1 = (e0 + PCHUNK < EE) ? e0 + PCHUNK : EE;
    for (int e = e0 + t; e < e1; e += 256)
        atomicAdd(&h[EI[EE + e] >> 8], 1);
    __syncthreads();
    for (int i = t; i < NB; i += 256)
        if (h[i]) atomicAdd(&bcount[i], h[i]);
}

__global__ __launch_bounds__(512) void k_bscan(const int* __restrict__ bcount,
                                               int* __restrict__ bstart,
                                               int* __restrict__ bcursor,
                                               int* __restrict__ row_start)
{
    __shared__ int s[512];
    int t = threadIdx.x;
    int v = (t < NB) ? bcount[t] : 0;
    s[t] = v;
    __syncthreads();
    for (int off = 1; off < 512; off <<= 1) {
        int u = (t >= off) ? s[t - off] : 0;
        __syncthreads();
        s[t] += u;
        __syncthreads();
    }
    if (t < NB) { int ex = s[t] - v; bstart[t] = ex; bcursor[t] = ex; }
    if (t == 0) { bstart[NB] = EE; row_start[NN] = EE; }
}

__global__ __launch_bounds__(256) void k_part(const int* __restrict__ EI,
                                              int* __restrict__ bcursor,
                                              int* __restrict__ ebuf)
{
    __shared__ int h[NB];
    __shared__ int cur[NB];
    const int t = threadIdx.x;
    for (int i = t; i < NB; i += 256) h[i] = 0;
    __syncthreads();
    const int e0 = blockIdx.x * PCHUNK;
    const int e1 = (e0 + PCHUNK < EE) ? e0 + PCHUNK : EE;
    for (int e = e0 + t; e < e1; e += 256)
        atomicAdd(&h[EI[EE + e] >> 8], 1);
    __syncthreads();
    for (int i = t; i < NB; i += 256)
        cur[i] = h[i] ? atomicAdd(&bcursor[i], h[i]) : 0;
    __syncthreads();
    for (int e = e0 + t; e < e1; e += 256) {
        int s = EI[e], d = EI[EE + e];
        int pos = atomicAdd(&cur[d >> 8], 1);
        ebuf[pos] = s | ((d & (NPB - 1)) << 17);
    }
}

// per-bucket: count -> block scan -> row_start -> fill ssrc (all block-local)
__global__ __launch_bounds__(256) void k_csrbucket(const int* __restrict__ ebuf,
                                                   const int* __restrict__ bstart,
                                                   int* __restrict__ row_start,
                                                   int* __restrict__ ssrc)
{
    __shared__ int cnt[NPB];
    __shared__ int cur[NPB];
    const int b = blockIdx.x, t = threadIdx.x;
    cnt[t] = 0;
    __syncthreads();
    const int e0 = bstart[b], e1 = bstart[b + 1];
    for (int e = e0 + t; e < e1; e += 256) {
        unsigned p = (unsigned)__builtin_nontemporal_load(&ebuf[e]);
        atomicAdd(&cnt[p >> 17], 1);
    }
    __syncthreads();
    int myc = cnt[t];
    // in-place Hillis-Steele inclusive scan
    for (int off = 1; off < 256; off <<= 1) {
        int u = (t >= off) ? cnt[t - off] : 0;
        __syncthreads();
        cnt[t] += u;
        __syncthreads();
    }
    int pos0 = e0 + cnt[t] - myc;        // global exclusive prefix
    int idx = b * NPB + t;
    if (idx < NN) row_start[idx] = pos0;
    cur[t] = pos0;
    __syncthreads();
    for (int e = e0 + t; e < e1; e += 256) {
        unsigned p = (unsigned)__builtin_nontemporal_load(&ebuf[e]);
        int pos = atomicAdd(&cur[p >> 17], 1);
        ssrc[pos] = (int)(p & 0x1FFFFu);
    }
}

// ---------------------------------------------------------------------------
// x cast + per-layer weight prep (BN scale/shift computed inline from stats)
// ---------------------------------------------------------------------------

__global__ __launch_bounds__(256) void k_xcast(const float* __restrict__ X,
                                               _Float16* __restrict__ Xh)
{
    int idx = blockIdx.x * 256 + threadIdx.x;
    const float4* src = (const float4*)X;
    float4 a = src[idx * 2], b = src[idx * 2 + 1];
    half8 o = { (_Float16)a.x, (_Float16)a.y, (_Float16)a.z, (_Float16)a.w,
                (_Float16)b.x, (_Float16)b.y, (_Float16)b.z, (_Float16)b.w };
    *(half8*)&Xh[idx * 8] = o;
}

__device__ __forceinline__ void bn_sc_sh(const float* colsum, const float* colsq,
                                         const float* g, const float* be, int k,
                                         float& sc, float& sh)
{
    float inv_n = 1.0f / (float)NN;
    float mu = colsum[k] * inv_n;
    float var = colsq[k] * inv_n - mu * mu;
    sc = g[k] * rsqrtf(var + BN_EPS);
    sh = be[k] - mu * sc;
}

// blocks 0-63: Wt1 ([n][k], BN-folded or embed slice); 64-127: Wt2; 128: cvec
__global__ __launch_bounds__(256) void k_prep(
    const float* __restrict__ W1, const float* __restrict__ W2,
    const float* __restrict__ colsum, const float* __restrict__ colsq,
    const float* __restrict__ g, const float* __restrict__ be,
    _Float16* __restrict__ Wt1, _Float16* __restrict__ Wt2,
    float* __restrict__ cvec, int l)
{
    int b = blockIdx.x, t = threadIdx.x;
    if (b < 64) {
        int idx = b * 256 + t;
        int n = idx >> 7, k = idx & 127;
        if (l == 0) {
            Wt1[idx] = (_Float16)W1[(200 + k) * 128 + n];
        } else {
            float sc, sh;
            bn_sc_sh(colsum, colsq, g, be, k, sc, sh);
            Wt1[idx] = (_Float16)(sc * W1[k * 128 + n]);
        }
    } else if (b < 128) {
        int idx = (b - 64) * 256 + t;
        int n = idx >> 7, k = idx & 127;
        Wt2[idx] = (_Float16)W2[k * 128 + n];
    } else if (t < 128) {
        float acc = 0.f;
        if (l != 0) {
            for (int k = 0; k < 128; ++k) {
                float sc, sh;
                bn_sc_sh(colsum, colsq, g, be, k, sc, sh);
                acc = fmaf(sh, W1[k * 128 + t], acc);
            }
        }
        cvec[t] = acc;
    }
}

// ---------------------------------------------------------------------------
// MFMA GEMM (A from global fp16, B-frags direct from L2-hot Wt[n][k])
// block 64x128, 4 waves 2x2, wave tile 32x64
// ---------------------------------------------------------------------------

#define MM_CORE_G(Ah, Wth)                                                   \
    const int lane = tid & 63;                                               \
    const int wv = tid >> 6;                                                 \
    const int ml = lane & 15;                                                \
    const int quad = lane >> 4;                                              \
    const int wr = wv >> 1, wc = wv & 1;                                     \
    floatx4 acc[2][4];                                                       \
    for (int r = 0; r < 2; ++r)                                              \
        for (int t = 0; t < 4; ++t)                                          \
            acc[r][t] = (floatx4){0.f, 0.f, 0.f, 0.f};                       \
    {                                                                        \
        const size_t ar0 = (size_t)(row0 + 32 * wr + ml) * 128;              \
        const size_t ar1 = ar0 + (size_t)16 * 128;                           \
        _Pragma("unroll")                                                    \
        for (int kq = 0; kq < 4; ++kq) {                                     \
            int k0 = kq * 32;                                                \
            half8 a0 = *(const half8*)&Ah[ar0 + k0 + quad * 8];              \
            half8 a1 = *(const half8*)&Ah[ar1 + k0 + quad * 8];              \
            _Pragma("unroll")                                                \
            for (int t = 0; t < 4; ++t) {                                    \
                half8 bf = *(const half8*)&Wth[(size_t)(64 * wc + 16 * t + ml) * 128 + k0 + quad * 8]; \
                acc[0][t] = __builtin_amdgcn_mfma_f32_16x16x32_f16(a0, bf, acc[0][t], 0, 0, 0); \
                acc[1][t] = __builtin_amdgcn_mfma_f32_16x16x32_f16(a1, bf, acc[1][t], 0, 0, 0); \
            }                                                                \
        }                                                                    \
    }

__global__ __launch_bounds__(256) void k_mm_embed(
    const _Float16* __restrict__ Ah, const _Float16* __restrict__ Wth,
    const int* __restrict__ Z, const float* __restrict__ W1,
    _Float16* __restrict__ Ph)
{
    const int tid = threadIdx.x;
    const int row0 = blockIdx.x * 64;
    MM_CORE_G(Ah, Wth)
    #pragma unroll
    for (int r = 0; r < 2; ++r)
        #pragma unroll
        for (int j = 0; j < 4; ++j) {
            int grow = row0 + 32 * wr + 16 * r + quad * 4 + j;
            if (grow < NN) {
                int zv = Z[grow];
                const float* w0 = &W1[zv * 128];
                const float* w1 = &W1[(100 + zv) * 128];
                #pragma unroll
                for (int t = 0; t < 4; ++t) {
                    int gcol = 64 * wc + 16 * t + ml;
                    float v = acc[r][t][j] + w0[gcol] + w1[gcol];
                    Ph[(size_t)grow * 128 + gcol] = (_Float16)v;
                }
            }
        }
}

__global__ __launch_bounds__(256) void k_mm1(
    const _Float16* __restrict__ Ah, const _Float16* __restrict__ Wth,
    _Float16* __restrict__ Ph)
{
    const int tid = threadIdx.x;
    const int row0 = blockIdx.x * 64;
    MM_CORE_G(Ah, Wth)
    #pragma unroll
    for (int r = 0; r < 2; ++r)
        #pragma unroll
        for (int j = 0; j < 4; ++j) {
            int grow = row0 + 32 * wr + 16 * r + quad * 4 + j;
            if (grow < NN) {
                #pragma unroll
                for (int t = 0; t < 4; ++t) {
                    int gcol = 64 * wc + 16 * t + ml;
                    Ph[(size_t)grow * 128 + gcol] = (_Float16)acc[r][t][j];
                }
            }
        }
}

// A' = relu(M @ Wt2 + b2) -> Oh; fused BN stats + per-graph pooled sums
__global__ __launch_bounds__(256) void k_mm2(
    const _Float16* __restrict__ Ah, const _Float16* __restrict__ Wth,
    const float* __restrict__ b2, const int* __restrict__ batch,
    _Float16* __restrict__ Oh,
    float* __restrict__ colsum, float* __restrict__ colsq,
    float* __restrict__ gpool)
{
    __shared__ float cs[128];
    __shared__ float cq[128];
    __shared__ float gp[8][128];
    const int tid = threadIdx.x;
    const int row0 = blockIdx.x * 64;
    for (int i = tid; i < 128; i += 256) { cs[i] = 0.f; cq[i] = 0.f; }
    for (int i = tid; i < 8 * 128; i += 256) (&gp[0][0])[i] = 0.f;
    __syncthreads();

    MM_CORE_G(Ah, Wth)

    const int gmin = batch[row0];
    const int rlast = (row0 + 63 < NN) ? row0 + 63 : NN - 1;
    const int span = batch[rlast] - gmin;
    float b2v[4];
    #pragma unroll
    for (int t = 0; t < 4; ++t) b2v[t] = b2[64 * wc + 16 * t + ml];
    float st[4] = {0.f, 0.f, 0.f, 0.f};
    float qt[4] = {0.f, 0.f, 0.f, 0.f};
    #pragma unroll
    for (int r = 0; r < 2; ++r)
        #pragma unroll
        for (int j = 0; j < 4; ++j) {
            int grow = row0 + 32 * wr + 16 * r + quad * 4 + j;
            if (grow < NN) {
                int rel = batch[grow] - gmin;
                #pragma unroll
                for (int t = 0; t < 4; ++t) {
                    int gcol = 64 * wc + 16 * t + ml;
                    float v = fmaxf(acc[r][t][j] + b2v[t], 0.f);
                    Oh[(size_t)grow * 128 + gcol] = (_Float16)v;
                    st[t] += v;
                    qt[t] += v * v;
                    if (rel < 8) atomicAdd(&gp[rel][gcol], v);
                    else atomicAdd(&gpool[(size_t)batch[grow] * 128 + gcol], v);
                }
            }
        }
    #pragma unroll
    for (int t = 0; t < 4; ++t) {
        int gcol = 64 * wc + 16 * t + ml;
        atomicAdd(&cs[gcol], st[t]);
        atomicAdd(&cq[gcol], qt[t]);
    }
    __syncthreads();
    if (tid < 128) {
        atomicAdd(&colsum[tid], cs[tid]);
        atomicAdd(&colsq[tid], cq[tid]);
        int smax = (span < 7) ? span : 7;
        for (int rel = 0; rel <= smax; ++rel)
            atomicAdd(&gpool[(size_t)(gmin + rel) * 128 + tid], gp[rel][tid]);
    }
}

// ---------------------------------------------------------------------------
// gather-aggregate (R6 form): 16 lanes/node, half8 loads, 4-edge unroll
// ---------------------------------------------------------------------------

__global__ __launch_bounds__(256) void k_aggregate(
    const _Float16* __restrict__ Ph, const int* __restrict__ row_start,
    const int* __restrict__ ssrc, const float* __restrict__ b1,
    const float* __restrict__ cvec, _Float16* __restrict__ Mh)
{
    int idx = blockIdx.x * 256 + threadIdx.x;
    int node = idx >> 4, q = idx & 15;
    if (node >= NN) return;
    int s0 = row_start[node], s1 = row_start[node + 1];
    float degp1 = (float)(s1 - s0 + 1);
    float acc[8];
    half8 pv = *(const half8*)&Ph[(size_t)node * 128 + q * 8];
    #pragma unroll
    for (int j = 0; j < 8; ++j)
        acc[j] = (float)pv[j] + fmaf(degp1, cvec[q * 8 + j], b1[q * 8 + j]);
    int e = s0;
    for (; e + 3 < s1; e += 4) {
        int sa = __builtin_nontemporal_load(&ssrc[e]);
        int sb = __builtin_nontemporal_load(&ssrc[e + 1]);
        int sc = __builtin_nontemporal_load(&ssrc[e + 2]);
        int sd = __builtin_nontemporal_load(&ssrc[e + 3]);
        half8 va = *(const half8*)&Ph[(size_t)sa * 128 + q * 8];
        half8 vb = *(const half8*)&Ph[(size_t)sb * 128 + q * 8];
        half8 vc = *(const half8*)&Ph[(size_t)sc * 128 + q * 8];
        half8 vd = *(const half8*)&Ph[(size_t)sd * 128 + q * 8];
        #pragma unroll
        for (int j = 0; j < 8; ++j)
            acc[j] += ((float)va[j] + (float)vb[j]) + ((float)vc[j] + (float)vd[j]);
    }
    for (; e < s1; ++e) {
        int sa = __builtin_nontemporal_load(&ssrc[e]);
        half8 va = *(const half8*)&Ph[(size_t)sa * 128 + q * 8];
        #pragma unroll
        for (int j = 0; j < 8; ++j) acc[j] += (float)va[j];
    }
    half8 o;
    #pragma unroll
    for (int j = 0; j < 8; ++j) o[j] = (_Float16)fmaxf(acc[j], 0.f);
    __builtin_nontemporal_store(o, (half8*)&Mh[(size_t)node * 128 + q * 8]);
}

// ---------------------------------------------------------------------------
// head: pooled (BN+mean from gpool/stats, inline) -> 2-layer MLP -> out
// ---------------------------------------------------------------------------

__global__ __launch_bounds__(128) void k_final(
    const float* __restrict__ gpool, const float* __restrict__ stats,
    const int* __restrict__ batch,
    const float* __restrict__ g0, const float* __restrict__ be0,
    const float* __restrict__ g1, const float* __restrict__ be1,
    const float* __restrict__ g2, const float* __restrict__ be2,
    const float* __restrict__ Wl1, const float* __restrict__ bl1,
    const float* __restrict__ Wl2, const float* __restrict__ bl2,
    float* __restrict__ out)
{
    __shared__ float pr[384];
    __shared__ float red[128];
    int g = blockIdx.x, j = threadIdx.x;
    int lo = 0, hi = NN;
    while (lo < hi) { int mid = (lo + hi) >> 1; if (batch[mid] < g) lo = mid + 1; else hi = mid; }
    int s = lo;
    lo = s; hi = NN;
    while (lo < hi) { int mid = (lo + hi) >> 1; if (batch[mid] < g + 1) lo = mid + 1; else hi = mid; }
    int cnt = lo - s;
    float inv = 1.0f / (float)(cnt > 0 ? cnt : 1);
    #pragma unroll
    for (int l = 0; l < 3; ++l) {
        const float* gl  = (l == 0) ? g0 : (l == 1) ? g1 : g2;
        const float* bel = (l == 0) ? be0 : (l == 1) ? be1 : be2;
        float sc, sh;
        bn_sc_sh(stats + l * 256, stats + l * 256 + 128, gl, bel, j, sc, sh);
        float gs = gpool[((size_t)l * GG + g) * 128 + j];
        pr[l * 128 + j] = fmaf(sc, gs * inv, sh);
    }
    __syncthreads();
    float acc = bl1[j];
    for (int k = 0; k < 384; ++k) acc = fmaf(pr[k], Wl1[k * 128 + j], acc);
    float r = fmaxf(acc, 0.f) * Wl2[j];
    red[j] = r;
    __syncthreads();
    for (int off = 64; off > 0; off >>= 1) {
        if (j < off) red[j] += red[j + off];
        __syncthreads();
    }
    if (j == 0) out[g] = red[0] + bl2[0];
}

extern "C" void kernel_launch(void* const* d_in, const int* in_sizes, int n_in,
                              void* d_out, int out_size, void* d_ws, size_t ws_size,
                              hipStream_t stream)
{
    const float* x     = (const float*)d_in[0];
    const int*   z     = (const int*)d_in[1];
    const int*   ei    = (const int*)d_in[2];
    const int*   batch = (const int*)d_in[3];
    const float* W1a[3] = {(const float*)d_in[4],  (const float*)d_in[10], (const float*)d_in[16]};
    const float* b1a[3] = {(const float*)d_in[5],  (const float*)d_in[11], (const float*)d_in[17]};
    const float* W2a[3] = {(const float*)d_in[6],  (const float*)d_in[12], (const float*)d_in[18]};
    const float* b2a[3] = {(const float*)d_in[7],  (const float*)d_in[13], (const float*)d_in[19]};
    const float* ga[3]  = {(const float*)d_in[8],  (const float*)d_in[14], (const float*)d_in[20]};
    const float* bea[3] = {(const float*)d_in[9],  (const float*)d_in[15], (const float*)d_in[21]};
    const float* Wl1 = (const float*)d_in[22];
    const float* bl1 = (const float*)d_in[23];
    const float* Wl2 = (const float*)d_in[24];
    const float* bl2 = (const float*)d_in[25];
    float* out = (float*)d_out;

    char* ws = (char*)d_ws;
    size_t off = 0;
    auto alloc = [&](size_t bytes) {
        void* p = ws + off;
        off += (bytes + 255) & ~(size_t)255;
        return p;
    };
    _Float16* Xh  = (_Float16*)alloc((size_t)NROWS_PAD * 128 * 2);
    _Float16* Ph  = (_Float16*)alloc((size_t)NROWS_PAD * 128 * 2);
    _Float16* Mh  = (_Float16*)alloc((size_t)NROWS_PAD * 128 * 2);
    _Float16* Ahb = (_Float16*)alloc((size_t)NROWS_PAD * 128 * 2);
    _Float16* Wt1 = (_Float16*)alloc((size_t)128 * 128 * 2);
    _Float16* Wt2 = (_Float16*)alloc((size_t)128 * 128 * 2);
    int*   ebuf     = (int*)alloc((size_t)EE * 4);
    int*   ssrc     = (int*)alloc((size_t)EE * 4);
    int*   row_st   = (int*)alloc((size_t)(NN + 1) * 4);
    int*   bcount   = (int*)alloc((size_t)NB * 4);
    int*   bstart   = (int*)alloc((size_t)(NB + 1) * 4);
    int*   bcursor  = (int*)alloc((size_t)NB * 4);
    float* cvec     = (float*)alloc(128 * 4);
    float* stats    = (float*)alloc(3 * 256 * 4);               // [3][colsum|colsq]
    float* gpool    = (float*)alloc((size_t)3 * GG * 128 * 4);  // contiguous after stats
    const int gemmBlocks = (NN + 63) / 64;           // 1563
    const int aggBlocks  = (NN * 16 + 255) / 256;    // 6250

    // ---- one-time per call ----
    hipMemsetAsync(stats, 0, 3 * 256 * 4 + (size_t)3 * GG * 128 * 4, stream);
    hipMemsetAsync(bcount, 0, (size_t)NB * 4, stream);
    k_xcast<<<(NN * 128 / 8 + 255) / 256, 256, 0, stream>>>(x, Xh);
    k_bhist<<<PBLOCKS, 256, 0, stream>>>(ei, bcount);
    k_bscan<<<1, 512, 0, stream>>>(bcount, bstart, bcursor, row_st);
    k_part<<<PBLOCKS, 256, 0, stream>>>(ei, bcursor, ebuf);
    k_csrbucket<<<NB, 256, 0, stream>>>(ebuf, bstart, row_st, ssrc);

    for (int l = 0; l < 3; ++l) {
        float* colsum = stats + l * 256;
        float* colsq  = stats + l * 256 + 128;
        const float* psum = (l > 0) ? stats + (l - 1) * 256 : stats;
        const float* psq  = (l > 0) ? stats + (l - 1) * 256 + 128 : stats + 128;
        const float* pg   = (l > 0) ? ga[l - 1] : ga[0];
        const float* pbe  = (l > 0) ? bea[l - 1] : bea[0];
        k_prep<<<129, 256, 0, stream>>>(W1a[l], W2a[l], psum, psq, pg, pbe,
                                        Wt1, Wt2, cvec, l);
        if (l == 0)
            k_mm_embed<<<gemmBlocks, 256, 0, stream>>>(Xh, Wt1, z, W1a[0], Ph);
        else
            k_mm1<<<gemmBlocks, 256, 0, stream>>>(Ahb, Wt1, Ph);
        k_aggregate<<<aggBlocks, 256, 0, stream>>>(Ph, row_st, ssrc, b1a[l], cvec, Mh);
        k_mm2<<<gemmBlocks, 256, 0, stream>>>(Mh, Wt2, b2a[l], batch, Ahb,
                                              colsum, colsq, gpool + (size_t)l * GG * 128);
    }
    k_final<<<GG, 128, 0, stream>>>(gpool, stats, batch,
                                    ga[0], bea[0], ga[1], bea[1], ga[2], bea[2],
                                    Wl1, bl1, Wl2, bl2, out);
}

// Round 9
// 759.367 us; speedup vs baseline: 1.0939x; 1.0939x over previous
//
#include <hip/hip_runtime.h>
#include <hip/hip_bf16.h>

#define NN 100000
#define NROWS_PAD 100032
#define EE 1600000
#define GG 512
#define NPB 256                                            // nodes per bucket
#define NB  ((NN + NPB - 1) / NPB)                         // 391 buckets
#define PCHUNK 4096                                        // edges per partition block
#define PBLOCKS ((EE + PCHUNK - 1) / PCHUNK)               // 391
static constexpr float BN_EPS = 1e-5f;

typedef _Float16 half8 __attribute__((ext_vector_type(8)));
typedef float floatx4 __attribute__((ext_vector_type(4)));

// ---------------------------------------------------------------------------
// CSR build (write-local). ebuf packed: src (bits 0-16) | (dst&255) << 17
// ---------------------------------------------------------------------------

__global__ __launch_bounds__(256) void k_bhist(const int* __restrict__ EI,
                                               int* __restrict__ bcount)
{
    __shared__ int h[NB];
    const int t = threadIdx.x;
    for (int i = t; i < NB; i += 256) h[i] = 0;
    __syncthreads();
    const int e0 = blockIdx.x * PCHUNK;
    const int e1 = (e0 + PCHUNK < EE) ? e0 + PCHUNK : EE;
    for (int e = e0 + t; e < e1; e += 256)
        atomicAdd(&h[EI[EE + e] >> 8], 1);
    __syncthreads();
    for (int i = t; i < NB; i += 256)
        if (h[i]) atomicAdd(&bcount[i], h[i]);
}

__global__ __launch_bounds__(512) void k_bscan(const int* __restrict__ bcount,
                                               int* __restrict__ bstart,
                                               int* __restrict__ bcursor,
                                               int* __restrict__ row_start)
{
    __shared__ int s[512];
    int t = threadIdx.x;
    int v = (t < NB) ? bcount[t] : 0;
    s[t] = v;
    __syncthreads();
    for (int off = 1; off < 512; off <<= 1) {
        int u = (t >= off) ? s[t - off] : 0;
        __syncthreads();
        s[t] += u;
        __syncthreads();
    }
    if (t < NB) { int ex = s[t] - v; bstart[t] = ex; bcursor[t] = ex; }
    if (t == 0) { bstart[NB] = EE; row_start[NN] = EE; }
}

__global__ __launch_bounds__(256) void k_part(const int* __restrict__ EI,
                                              int* __restrict__ bcursor,
                                              int* __restrict__ ebuf)
{
    __shared__ int h[NB];
    __shared__ int cur[NB];
    const int t = threadIdx.x;
    for (int i = t; i < NB; i += 256) h[i] = 0;
    __syncthreads();
    const int e0 = blockIdx.x * PCHUNK;
    const int e1 = (e0 + PCHUNK < EE) ? e0 + PCHUNK : EE;
    for (int e = e0 + t; e < e1; e += 256)
        atomicAdd(&h[EI[EE + e] >> 8], 1);
    __syncthreads();
    for (int i = t; i < NB; i += 256)
        cur[i] = h[i] ? atomicAdd(&bcursor[i], h[i]) : 0;
    __syncthreads();
    for (int e = e0 + t; e < e1; e += 256) {
        int s = EI[e], d = EI[EE + e];
        int pos = atomicAdd(&cur[d >> 8], 1);
        ebuf[pos] = s | ((d & (NPB - 1)) << 17);
    }
}

// per-bucket: count -> block scan -> row_start -> fill ssrc (all block-local)
__global__ __launch_bounds__(256) void k_csrbucket(const int* __restrict__ ebuf,
                                                   const int* __restrict__ bstart,
                                                   int* __restrict__ row_start,
                                                   int* __restrict__ ssrc)
{
    __shared__ int cnt[NPB];
    __shared__ int cur[NPB];
    const int b = blockIdx.x, t = threadIdx.x;
    cnt[t] = 0;
    __syncthreads();
    const int e0 = bstart[b], e1 = bstart[b + 1];
    for (int e = e0 + t; e < e1; e += 256) {
        unsigned p = (unsigned)__builtin_nontemporal_load(&ebuf[e]);
        atomicAdd(&cnt[p >> 17], 1);
    }
    __syncthreads();
    int myc = cnt[t];
    for (int off = 1; off < 256; off <<= 1) {
        int u = (t >= off) ? cnt[t - off] : 0;
        __syncthreads();
        cnt[t] += u;
        __syncthreads();
    }
    int pos0 = e0 + cnt[t] - myc;        // global exclusive prefix
    int idx = b * NPB + t;
    if (idx < NN) row_start[idx] = pos0;
    cur[t] = pos0;
    __syncthreads();
    for (int e = e0 + t; e < e1; e += 256) {
        unsigned p = (unsigned)__builtin_nontemporal_load(&ebuf[e]);
        int pos = atomicAdd(&cur[p >> 17], 1);
        ssrc[pos] = (int)(p & 0x1FFFFu);
    }
}

// ---------------------------------------------------------------------------
// x cast + per-layer weight prep (BN scale/shift computed inline from stats)
// ---------------------------------------------------------------------------

__global__ __launch_bounds__(256) void k_xcast(const float* __restrict__ X,
                                               _Float16* __restrict__ Xh)
{
    int idx = blockIdx.x * 256 + threadIdx.x;
    const float4* src = (const float4*)X;
    float4 a = src[idx * 2], b = src[idx * 2 + 1];
    half8 o = { (_Float16)a.x, (_Float16)a.y, (_Float16)a.z, (_Float16)a.w,
                (_Float16)b.x, (_Float16)b.y, (_Float16)b.z, (_Float16)b.w };
    *(half8*)&Xh[idx * 8] = o;
}

__device__ __forceinline__ void bn_sc_sh(const float* colsum, const float* colsq,
                                         const float* g, const float* be, int k,
                                         float& sc, float& sh)
{
    float inv_n = 1.0f / (float)NN;
    float mu = colsum[k] * inv_n;
    float var = colsq[k] * inv_n - mu * mu;
    sc = g[k] * rsqrtf(var + BN_EPS);
    sh = be[k] - mu * sc;
}

// blocks 0-63: Wt1 ([n][k], BN-folded or embed slice); 64-127: Wt2; 128: cvec
__global__ __launch_bounds__(256) void k_prep(
    const float* __restrict__ W1, const float* __restrict__ W2,
    const float* __restrict__ colsum, const float* __restrict__ colsq,
    const float* __restrict__ g, const float* __restrict__ be,
    _Float16* __restrict__ Wt1, _Float16* __restrict__ Wt2,
    float* __restrict__ cvec, int l)
{
    int b = blockIdx.x, t = threadIdx.x;
    if (b < 64) {
        int idx = b * 256 + t;
        int n = idx >> 7, k = idx & 127;
        if (l == 0) {
            Wt1[idx] = (_Float16)W1[(200 + k) * 128 + n];
        } else {
            float sc, sh;
            bn_sc_sh(colsum, colsq, g, be, k, sc, sh);
            Wt1[idx] = (_Float16)(sc * W1[k * 128 + n]);
        }
    } else if (b < 128) {
        int idx = (b - 64) * 256 + t;
        int n = idx >> 7, k = idx & 127;
        Wt2[idx] = (_Float16)W2[k * 128 + n];
    } else if (t < 128) {
        float acc = 0.f;
        if (l != 0) {
            for (int k = 0; k < 128; ++k) {
                float sc, sh;
                bn_sc_sh(colsum, colsq, g, be, k, sc, sh);
                acc = fmaf(sh, W1[k * 128 + t], acc);
            }
        }
        cvec[t] = acc;
    }
}

// ---------------------------------------------------------------------------
// MFMA GEMM (A from global fp16, B-frags direct from L2-hot Wt[n][k])
// block 64x128, 4 waves 2x2, wave tile 32x64
// ---------------------------------------------------------------------------

#define MM_CORE_G(Ah, Wth)                                                   \
    const int lane = tid & 63;                                               \
    const int wv = tid >> 6;                                                 \
    const int ml = lane & 15;                                                \
    const int quad = lane >> 4;                                              \
    const int wr = wv >> 1, wc = wv & 1;                                     \
    floatx4 acc[2][4];                                                       \
    for (int r = 0; r < 2; ++r)                                              \
        for (int t = 0; t < 4; ++t)                                          \
            acc[r][t] = (floatx4){0.f, 0.f, 0.f, 0.f};                       \
    {                                                                        \
        const size_t ar0 = (size_t)(row0 + 32 * wr + ml) * 128;              \
        const size_t ar1 = ar0 + (size_t)16 * 128;                           \
        _Pragma("unroll")                                                    \
        for (int kq = 0; kq < 4; ++kq) {                                     \
            int k0 = kq * 32;                                                \
            half8 a0 = *(const half8*)&Ah[ar0 + k0 + quad * 8];              \
            half8 a1 = *(const half8*)&Ah[ar1 + k0 + quad * 8];              \
            _Pragma("unroll")                                                \
            for (int t = 0; t < 4; ++t) {                                    \
                half8 bf = *(const half8*)&Wth[(size_t)(64 * wc + 16 * t + ml) * 128 + k0 + quad * 8]; \
                acc[0][t] = __builtin_amdgcn_mfma_f32_16x16x32_f16(a0, bf, acc[0][t], 0, 0, 0); \
                acc[1][t] = __builtin_amdgcn_mfma_f32_16x16x32_f16(a1, bf, acc[1][t], 0, 0, 0); \
            }                                                                \
        }                                                                    \
    }

__global__ __launch_bounds__(256) void k_mm_embed(
    const _Float16* __restrict__ Ah, const _Float16* __restrict__ Wth,
    const int* __restrict__ Z, const float* __restrict__ W1,
    _Float16* __restrict__ Ph)
{
    const int tid = threadIdx.x;
    const int row0 = blockIdx.x * 64;
    MM_CORE_G(Ah, Wth)
    #pragma unroll
    for (int r = 0; r < 2; ++r)
        #pragma unroll
        for (int j = 0; j < 4; ++j) {
            int grow = row0 + 32 * wr + 16 * r + quad * 4 + j;
            if (grow < NN) {
                int zv = Z[grow];
                const float* w0 = &W1[zv * 128];
                const float* w1 = &W1[(100 + zv) * 128];
                #pragma unroll
                for (int t = 0; t < 4; ++t) {
                    int gcol = 64 * wc + 16 * t + ml;
                    float v = acc[r][t][j] + w0[gcol] + w1[gcol];
                    Ph[(size_t)grow * 128 + gcol] = (_Float16)v;
                }
            }
        }
}

__global__ __launch_bounds__(256) void k_mm1(
    const _Float16* __restrict__ Ah, const _Float16* __restrict__ Wth,
    _Float16* __restrict__ Ph)
{
    const int tid = threadIdx.x;
    const int row0 = blockIdx.x * 64;
    MM_CORE_G(Ah, Wth)
    #pragma unroll
    for (int r = 0; r < 2; ++r)
        #pragma unroll
        for (int j = 0; j < 4; ++j) {
            int grow = row0 + 32 * wr + 16 * r + quad * 4 + j;
            if (grow < NN) {
                #pragma unroll
                for (int t = 0; t < 4; ++t) {
                    int gcol = 64 * wc + 16 * t + ml;
                    Ph[(size_t)grow * 128 + gcol] = (_Float16)acc[r][t][j];
                }
            }
        }
}

// A' = relu(M @ Wt2 + b2) -> Oh; fused BN stats only
__global__ __launch_bounds__(256) void k_mm2(
    const _Float16* __restrict__ Ah, const _Float16* __restrict__ Wth,
    const float* __restrict__ b2, _Float16* __restrict__ Oh,
    float* __restrict__ colsum, float* __restrict__ colsq)
{
    __shared__ float cs[128];
    __shared__ float cq[128];
    const int tid = threadIdx.x;
    const int row0 = blockIdx.x * 64;
    if (tid < 128) { cs[tid] = 0.f; cq[tid] = 0.f; }
    __syncthreads();

    MM_CORE_G(Ah, Wth)

    float b2v[4];
    #pragma unroll
    for (int t = 0; t < 4; ++t) b2v[t] = b2[64 * wc + 16 * t + ml];
    float st[4] = {0.f, 0.f, 0.f, 0.f};
    float qt[4] = {0.f, 0.f, 0.f, 0.f};
    #pragma unroll
    for (int r = 0; r < 2; ++r)
        #pragma unroll
        for (int j = 0; j < 4; ++j) {
            int grow = row0 + 32 * wr + 16 * r + quad * 4 + j;
            if (grow < NN) {
                #pragma unroll
                for (int t = 0; t < 4; ++t) {
                    int gcol = 64 * wc + 16 * t + ml;
                    float v = fmaxf(acc[r][t][j] + b2v[t], 0.f);
                    Oh[(size_t)grow * 128 + gcol] = (_Float16)v;
                    st[t] += v;
                    qt[t] += v * v;
                }
            }
        }
    #pragma unroll
    for (int t = 0; t < 4; ++t) {
        int gcol = 64 * wc + 16 * t + ml;
        atomicAdd(&cs[gcol], st[t]);
        atomicAdd(&cq[gcol], qt[t]);
    }
    __syncthreads();
    if (tid < 128) {
        atomicAdd(&colsum[tid], cs[tid]);
        atomicAdd(&colsq[tid], cq[tid]);
    }
}

// ---------------------------------------------------------------------------
// gather-aggregate: 16 lanes/node, half8 loads, 8-edge unroll
// ---------------------------------------------------------------------------

__global__ __launch_bounds__(256) void k_aggregate(
    const _Float16* __restrict__ Ph, const int* __restrict__ row_start,
    const int* __restrict__ ssrc, const float* __restrict__ b1,
    const float* __restrict__ cvec, _Float16* __restrict__ Mh)
{
    int idx = blockIdx.x * 256 + threadIdx.x;
    int node = idx >> 4, q = idx & 15;
    if (node >= NN) return;
    int s0 = row_start[node], s1 = row_start[node + 1];
    float degp1 = (float)(s1 - s0 + 1);
    float acc[8];
    half8 pv = *(const half8*)&Ph[(size_t)node * 128 + q * 8];
    #pragma unroll
    for (int j = 0; j < 8; ++j)
        acc[j] = (float)pv[j] + fmaf(degp1, cvec[q * 8 + j], b1[q * 8 + j]);
    int e = s0;
    for (; e + 7 < s1; e += 8) {
        int sidx[8];
        #pragma unroll
        for (int u = 0; u < 8; ++u)
            sidx[u] = __builtin_nontemporal_load(&ssrc[e + u]);
        half8 v[8];
        #pragma unroll
        for (int u = 0; u < 8; ++u)
            v[u] = *(const half8*)&Ph[(size_t)sidx[u] * 128 + q * 8];
        #pragma unroll
        for (int j = 0; j < 8; ++j)
            acc[j] += (((float)v[0][j] + (float)v[1][j]) + ((float)v[2][j] + (float)v[3][j]))
                    + (((float)v[4][j] + (float)v[5][j]) + ((float)v[6][j] + (float)v[7][j]));
    }
    for (; e + 1 < s1; e += 2) {
        int sa = __builtin_nontemporal_load(&ssrc[e]);
        int sb = __builtin_nontemporal_load(&ssrc[e + 1]);
        half8 va = *(const half8*)&Ph[(size_t)sa * 128 + q * 8];
        half8 vb = *(const half8*)&Ph[(size_t)sb * 128 + q * 8];
        #pragma unroll
        for (int j = 0; j < 8; ++j) acc[j] += (float)va[j] + (float)vb[j];
    }
    if (e < s1) {
        int sa = __builtin_nontemporal_load(&ssrc[e]);
        half8 va = *(const half8*)&Ph[(size_t)sa * 128 + q * 8];
        #pragma unroll
        for (int j = 0; j < 8; ++j) acc[j] += (float)va[j];
    }
    half8 o;
    #pragma unroll
    for (int j = 0; j < 8; ++j) o[j] = (_Float16)fmaxf(acc[j], 0.f);
    __builtin_nontemporal_store(o, (half8*)&Mh[(size_t)node * 128 + q * 8]);
}

// ---------------------------------------------------------------------------
// mean-pool per graph (BN sc/sh inline); 8 row-groups x 16 col-segs
// ---------------------------------------------------------------------------

__global__ __launch_bounds__(128) void k_pool(
    const _Float16* __restrict__ Ah, const int* __restrict__ batch,
    const float* __restrict__ colsum, const float* __restrict__ colsq,
    const float* __restrict__ g_, const float* __restrict__ be,
    float* __restrict__ pooled, int loff)
{
    __shared__ float red[8][128];
    int g = blockIdx.x;
    int t = threadIdx.x;
    int rg = t >> 4, seg = t & 15;
    int lo = 0, hi = NN;
    while (lo < hi) { int mid = (lo + hi) >> 1; if (batch[mid] < g) lo = mid + 1; else hi = mid; }
    int s = lo;
    lo = s; hi = NN;
    while (lo < hi) { int mid = (lo + hi) >> 1; if (batch[mid] < g + 1) lo = mid + 1; else hi = mid; }
    int e = lo;
    float acc[8] = {};
    for (int i = s + rg; i < e; i += 8) {
        half8 v = *(const half8*)&Ah[(size_t)i * 128 + seg * 8];
        #pragma unroll
        for (int j = 0; j < 8; ++j) acc[j] += (float)v[j];
    }
    #pragma unroll
    for (int j = 0; j < 8; ++j) red[rg][seg * 8 + j] = acc[j];
    __syncthreads();
    int cnt = e - s;
    float inv = 1.0f / (float)(cnt > 0 ? cnt : 1);
    if (t < 128) {
        float s_ = 0.f;
        #pragma unroll
        for (int r = 0; r < 8; ++r) s_ += red[r][t];
        float sc, sh;
        bn_sc_sh(colsum, colsq, g_, be, t, sc, sh);
        pooled[g * 384 + loff + t] = fmaf(sc, s_ * inv, sh);
    }
}

__global__ __launch_bounds__(128) void k_final(
    const float* __restrict__ pooled,
    const float* __restrict__ Wl1, const float* __restrict__ bl1,
    const float* __restrict__ Wl2, const float* __restrict__ bl2,
    float* __restrict__ out)
{
    __shared__ float pr[384];
    __shared__ float red[128];
    int g = blockIdx.x, j = threadIdx.x;
    for (int i = j; i < 384; i += 128) pr[i] = pooled[g * 384 + i];
    __syncthreads();
    float acc = bl1[j];
    for (int k = 0; k < 384; ++k) acc = fmaf(pr[k], Wl1[k * 128 + j], acc);
    float r = fmaxf(acc, 0.f) * Wl2[j];
    red[j] = r;
    __syncthreads();
    for (int off = 64; off > 0; off >>= 1) {
        if (j < off) red[j] += red[j + off];
        __syncthreads();
    }
    if (j == 0) out[g] = red[0] + bl2[0];
}

extern "C" void kernel_launch(void* const* d_in, const int* in_sizes, int n_in,
                              void* d_out, int out_size, void* d_ws, size_t ws_size,
                              hipStream_t stream)
{
    const float* x     = (const float*)d_in[0];
    const int*   z     = (const int*)d_in[1];
    const int*   ei    = (const int*)d_in[2];
    const int*   batch = (const int*)d_in[3];
    const float* W1a[3] = {(const float*)d_in[4],  (const float*)d_in[10], (const float*)d_in[16]};
    const float* b1a[3] = {(const float*)d_in[5],  (const float*)d_in[11], (const float*)d_in[17]};
    const float* W2a[3] = {(const float*)d_in[6],  (const float*)d_in[12], (const float*)d_in[18]};
    const float* b2a[3] = {(const float*)d_in[7],  (const float*)d_in[13], (const float*)d_in[19]};
    const float* ga[3]  = {(const float*)d_in[8],  (const float*)d_in[14], (const float*)d_in[20]};
    const float* bea[3] = {(const float*)d_in[9],  (const float*)d_in[15], (const float*)d_in[21]};
    const float* Wl1 = (const float*)d_in[22];
    const float* bl1 = (const float*)d_in[23];
    const float* Wl2 = (const float*)d_in[24];
    const float* bl2 = (const float*)d_in[25];
    float* out = (float*)d_out;

    char* ws = (char*)d_ws;
    size_t off = 0;
    auto alloc = [&](size_t bytes) {
        void* p = ws + off;
        off += (bytes + 255) & ~(size_t)255;
        return p;
    };
    _Float16* Xh  = (_Float16*)alloc((size_t)NROWS_PAD * 128 * 2);
    _Float16* Ph  = (_Float16*)alloc((size_t)NROWS_PAD * 128 * 2);
    _Float16* Mh  = (_Float16*)alloc((size_t)NROWS_PAD * 128 * 2);
    _Float16* Ahb = (_Float16*)alloc((size_t)NROWS_PAD * 128 * 2);
    _Float16* Wt1 = (_Float16*)alloc((size_t)128 * 128 * 2);
    _Float16* Wt2 = (_Float16*)alloc((size_t)128 * 128 * 2);
    int*   ebuf     = (int*)alloc((size_t)EE * 4);
    int*   ssrc     = (int*)alloc((size_t)EE * 4);
    int*   row_st   = (int*)alloc((size_t)(NN + 1) * 4);
    int*   bcount   = (int*)alloc((size_t)NB * 4);
    int*   bstart   = (int*)alloc((size_t)(NB + 1) * 4);
    int*   bcursor  = (int*)alloc((size_t)NB * 4);
    float* cvec     = (float*)alloc(128 * 4);
    float* stats    = (float*)alloc(3 * 256 * 4);   // [3][colsum|colsq]
    float* pooled   = (float*)alloc((size_t)GG * 384 * 4);

    const int gemmBlocks = (NN + 63) / 64;           // 1563
    const int aggBlocks  = (NN * 16 + 255) / 256;    // 6250

    // ---- one-time per call ----
    hipMemsetAsync(stats, 0, 3 * 256 * 4, stream);
    hipMemsetAsync(bcount, 0, (size_t)NB * 4, stream);
    k_xcast<<<(NN * 128 / 8 + 255) / 256, 256, 0, stream>>>(x, Xh);
    k_bhist<<<PBLOCKS, 256, 0, stream>>>(ei, bcount);
    k_bscan<<<1, 512, 0, stream>>>(bcount, bstart, bcursor, row_st);
    k_part<<<PBLOCKS, 256, 0, stream>>>(ei, bcursor, ebuf);
    k_csrbucket<<<NB, 256, 0, stream>>>(ebuf, bstart, row_st, ssrc);

    for (int l = 0; l < 3; ++l) {
        float* colsum = stats + l * 256;
        float* colsq  = stats + l * 256 + 128;
        const float* psum = (l > 0) ? stats + (l - 1) * 256 : stats;
        const float* psq  = (l > 0) ? stats + (l - 1) * 256 + 128 : stats + 128;
        const float* pg   = (l > 0) ? ga[l - 1] : ga[0];
        const float* pbe  = (l > 0) ? bea[l - 1] : bea[0];
        k_prep<<<129, 256, 0, stream>>>(W1a[l], W2a[l], psum, psq, pg, pbe,
                                        Wt1, Wt2, cvec, l);
        if (l == 0)
            k_mm_embed<<<gemmBlocks, 256, 0, stream>>>(Xh, Wt1, z, W1a[0], Ph);
        else
            k_mm1<<<gemmBlocks, 256, 0, stream>>>(Ahb, Wt1, Ph);
        k_aggregate<<<aggBlocks, 256, 0, stream>>>(Ph, row_st, ssrc, b1a[l], cvec, Mh);
        k_mm2<<<gemmBlocks, 256, 0, stream>>>(Mh, Wt2, b2a[l], Ahb, colsum, colsq);
        k_pool<<<GG, 128, 0, stream>>>(Ahb, batch, colsum, colsq, ga[l], bea[l],
                                       pooled, l * 128);
    }
    k_final<<<GG, 128, 0, stream>>>(pooled, Wl1, bl1, Wl2, bl2, out);
}

// Round 10
// 699.832 us; speedup vs baseline: 1.1870x; 1.0851x over previous
//
#include <hip/hip_runtime.h>
#include <hip/hip_bf16.h>

#define NN 100000
#define NROWS_PAD 100032
#define EE 1600000
#define GG 512
#define NPB 256                                            // nodes per bucket
#define NB  ((NN + NPB - 1) / NPB)                         // 391 buckets
#define PCHUNK 4096                                        // edges per partition block
#define PBLOCKS ((EE + PCHUNK - 1) / PCHUNK)               // 391
#define SBANK 8                                            // stats replication banks
static constexpr float BN_EPS = 1e-5f;

typedef _Float16 half8 __attribute__((ext_vector_type(8)));
typedef float floatx4 __attribute__((ext_vector_type(4)));

// ---------------------------------------------------------------------------
// CSR build (write-local). ebuf packed: src (bits 0-16) | (dst&255) << 17
// ---------------------------------------------------------------------------

__global__ __launch_bounds__(256) void k_bhist(const int* __restrict__ EI,
                                               int* __restrict__ bcount)
{
    __shared__ int h[NB];
    const int t = threadIdx.x;
    for (int i = t; i < NB; i += 256) h[i] = 0;
    __syncthreads();
    const int e0 = blockIdx.x * PCHUNK;
    const int e1 = (e0 + PCHUNK < EE) ? e0 + PCHUNK : EE;
    for (int e = e0 + t; e < e1; e += 256)
        atomicAdd(&h[EI[EE + e] >> 8], 1);
    __syncthreads();
    for (int i = t; i < NB; i += 256)
        if (h[i]) atomicAdd(&bcount[i], h[i]);
}

__global__ __launch_bounds__(512) void k_bscan(const int* __restrict__ bcount,
                                               int* __restrict__ bstart,
                                               int* __restrict__ bcursor,
                                               int* __restrict__ row_start)
{
    __shared__ int s[512];
    int t = threadIdx.x;
    int v = (t < NB) ? bcount[t] : 0;
    s[t] = v;
    __syncthreads();
    for (int off = 1; off < 512; off <<= 1) {
        int u = (t >= off) ? s[t - off] : 0;
        __syncthreads();
        s[t] += u;
        __syncthreads();
    }
    if (t < NB) { int ex = s[t] - v; bstart[t] = ex; bcursor[t] = ex; }
    if (t == 0) { bstart[NB] = EE; row_start[NN] = EE; }
}

__global__ __launch_bounds__(256) void k_part(const int* __restrict__ EI,
                                              int* __restrict__ bcursor,
                                              int* __restrict__ ebuf)
{
    __shared__ int h[NB];
    __shared__ int cur[NB];
    const int t = threadIdx.x;
    for (int i = t; i < NB; i += 256) h[i] = 0;
    __syncthreads();
    const int e0 = blockIdx.x * PCHUNK;
    const int e1 = (e0 + PCHUNK < EE) ? e0 + PCHUNK : EE;
    for (int e = e0 + t; e < e1; e += 256)
        atomicAdd(&h[EI[EE + e] >> 8], 1);
    __syncthreads();
    for (int i = t; i < NB; i += 256)
        cur[i] = h[i] ? atomicAdd(&bcursor[i], h[i]) : 0;
    __syncthreads();
    for (int e = e0 + t; e < e1; e += 256) {
        int s = EI[e], d = EI[EE + e];
        int pos = atomicAdd(&cur[d >> 8], 1);
        ebuf[pos] = s | ((d & (NPB - 1)) << 17);
    }
}

// per-bucket: count -> block scan -> row_start -> fill ssrc (all block-local)
__global__ __launch_bounds__(256) void k_csrbucket(const int* __restrict__ ebuf,
                                                   const int* __restrict__ bstart,
                                                   int* __restrict__ row_start,
                                                   int* __restrict__ ssrc)
{
    __shared__ int cnt[NPB];
    __shared__ int cur[NPB];
    const int b = blockIdx.x, t = threadIdx.x;
    cnt[t] = 0;
    __syncthreads();
    const int e0 = bstart[b], e1 = bstart[b + 1];
    for (int e = e0 + t; e < e1; e += 256) {
        unsigned p = (unsigned)__builtin_nontemporal_load(&ebuf[e]);
        atomicAdd(&cnt[p >> 17], 1);
    }
    __syncthreads();
    int myc = cnt[t];
    for (int off = 1; off < 256; off <<= 1) {
        int u = (t >= off) ? cnt[t - off] : 0;
        __syncthreads();
        cnt[t] += u;
        __syncthreads();
    }
    int pos0 = e0 + cnt[t] - myc;        // global exclusive prefix
    int idx = b * NPB + t;
    if (idx < NN) row_start[idx] = pos0;
    cur[t] = pos0;
    __syncthreads();
    for (int e = e0 + t; e < e1; e += 256) {
        unsigned p = (unsigned)__builtin_nontemporal_load(&ebuf[e]);
        int pos = atomicAdd(&cur[p >> 17], 1);
        ssrc[pos] = (int)(p & 0x1FFFFu);
    }
}

// ---------------------------------------------------------------------------
// x cast + per-layer weight prep (BN scale/shift from 8-bank stats, inline)
// ---------------------------------------------------------------------------

__global__ __launch_bounds__(256) void k_xcast(const float* __restrict__ X,
                                               _Float16* __restrict__ Xh)
{
    int idx = blockIdx.x * 256 + threadIdx.x;
    const float4* src = (const float4*)X;
    float4 a = src[idx * 2], b = src[idx * 2 + 1];
    half8 o = { (_Float16)a.x, (_Float16)a.y, (_Float16)a.z, (_Float16)a.w,
                (_Float16)b.x, (_Float16)b.y, (_Float16)b.z, (_Float16)b.w };
    *(half8*)&Xh[idx * 8] = o;
}

// statsL: [SBANK][256] (colsum | colsq per bank)
__device__ __forceinline__ void bn_sc_sh(const float* statsL,
                                         const float* g, const float* be, int k,
                                         float& sc, float& sh)
{
    float cs = 0.f, cq = 0.f;
    #pragma unroll
    for (int b = 0; b < SBANK; ++b) {
        cs += statsL[b * 256 + k];
        cq += statsL[b * 256 + 128 + k];
    }
    float inv_n = 1.0f / (float)NN;
    float mu = cs * inv_n;
    float var = cq * inv_n - mu * mu;
    sc = g[k] * rsqrtf(var + BN_EPS);
    sh = be[k] - mu * sc;
}

// blocks 0-63: Wt1 ([n][k], BN-folded or embed slice); 64-127: Wt2; 128: cvec
__global__ __launch_bounds__(256) void k_prep(
    const float* __restrict__ W1, const float* __restrict__ W2,
    const float* __restrict__ statsPrev,
    const float* __restrict__ g, const float* __restrict__ be,
    _Float16* __restrict__ Wt1, _Float16* __restrict__ Wt2,
    float* __restrict__ cvec, int l)
{
    int b = blockIdx.x, t = threadIdx.x;
    if (b < 64) {
        int idx = b * 256 + t;
        int n = idx >> 7, k = idx & 127;
        if (l == 0) {
            Wt1[idx] = (_Float16)W1[(200 + k) * 128 + n];
        } else {
            float sc, sh;
            bn_sc_sh(statsPrev, g, be, k, sc, sh);
            Wt1[idx] = (_Float16)(sc * W1[k * 128 + n]);
        }
    } else if (b < 128) {
        int idx = (b - 64) * 256 + t;
        int n = idx >> 7, k = idx & 127;
        Wt2[idx] = (_Float16)W2[k * 128 + n];
    } else if (t < 128) {
        float acc = 0.f;
        if (l != 0) {
            for (int k = 0; k < 128; ++k) {
                float sc, sh;
                bn_sc_sh(statsPrev, g, be, k, sc, sh);
                acc = fmaf(sh, W1[k * 128 + t], acc);
            }
        }
        cvec[t] = acc;
    }
}

// ---------------------------------------------------------------------------
// MFMA GEMM (A from global fp16, B-frags direct from L2-hot Wt[n][k])
// block 64x128, 4 waves 2x2, wave tile 32x64
// ---------------------------------------------------------------------------

#define MM_CORE_G(Ah, Wth)                                                   \
    const int lane = tid & 63;                                               \
    const int wv = tid >> 6;                                                 \
    const int ml = lane & 15;                                                \
    const int quad = lane >> 4;                                              \
    const int wr = wv >> 1, wc = wv & 1;                                     \
    floatx4 acc[2][4];                                                       \
    for (int r = 0; r < 2; ++r)                                              \
        for (int t = 0; t < 4; ++t)                                          \
            acc[r][t] = (floatx4){0.f, 0.f, 0.f, 0.f};                       \
    {                                                                        \
        const size_t ar0 = (size_t)(row0 + 32 * wr + ml) * 128;              \
        const size_t ar1 = ar0 + (size_t)16 * 128;                           \
        _Pragma("unroll")                                                    \
        for (int kq = 0; kq < 4; ++kq) {                                     \
            int k0 = kq * 32;                                                \
            half8 a0 = *(const half8*)&Ah[ar0 + k0 + quad * 8];              \
            half8 a1 = *(const half8*)&Ah[ar1 + k0 + quad * 8];              \
            _Pragma("unroll")                                                \
            for (int t = 0; t < 4; ++t) {                                    \
                half8 bf = *(const half8*)&Wth[(size_t)(64 * wc + 16 * t + ml) * 128 + k0 + quad * 8]; \
                acc[0][t] = __builtin_amdgcn_mfma_f32_16x16x32_f16(a0, bf, acc[0][t], 0, 0, 0); \
                acc[1][t] = __builtin_amdgcn_mfma_f32_16x16x32_f16(a1, bf, acc[1][t], 0, 0, 0); \
            }                                                                \
        }                                                                    \
    }

__global__ __launch_bounds__(256) void k_mm_embed(
    const _Float16* __restrict__ Ah, const _Float16* __restrict__ Wth,
    const int* __restrict__ Z, const float* __restrict__ W1,
    _Float16* __restrict__ Ph)
{
    const int tid = threadIdx.x;
    const int row0 = blockIdx.x * 64;
    MM_CORE_G(Ah, Wth)
    #pragma unroll
    for (int r = 0; r < 2; ++r)
        #pragma unroll
        for (int j = 0; j < 4; ++j) {
            int grow = row0 + 32 * wr + 16 * r + quad * 4 + j;
            if (grow < NN) {
                int zv = Z[grow];
                const float* w0 = &W1[zv * 128];
                const float* w1 = &W1[(100 + zv) * 128];
                #pragma unroll
                for (int t = 0; t < 4; ++t) {
                    int gcol = 64 * wc + 16 * t + ml;
                    float v = acc[r][t][j] + w0[gcol] + w1[gcol];
                    Ph[(size_t)grow * 128 + gcol] = (_Float16)v;
                }
            }
        }
}

__global__ __launch_bounds__(256) void k_mm1(
    const _Float16* __restrict__ Ah, const _Float16* __restrict__ Wth,
    _Float16* __restrict__ Ph)
{
    const int tid = threadIdx.x;
    const int row0 = blockIdx.x * 64;
    MM_CORE_G(Ah, Wth)
    #pragma unroll
    for (int r = 0; r < 2; ++r)
        #pragma unroll
        for (int j = 0; j < 4; ++j) {
            int grow = row0 + 32 * wr + 16 * r + quad * 4 + j;
            if (grow < NN) {
                #pragma unroll
                for (int t = 0; t < 4; ++t) {
                    int gcol = 64 * wc + 16 * t + ml;
                    Ph[(size_t)grow * 128 + gcol] = (_Float16)acc[r][t][j];
                }
            }
        }
}

// A' = relu(M @ Wt2 + b2) -> Oh; BN stats into 8-bank replicated buffer
__global__ __launch_bounds__(256) void k_mm2(
    const _Float16* __restrict__ Ah, const _Float16* __restrict__ Wth,
    const float* __restrict__ b2, _Float16* __restrict__ Oh,
    float* __restrict__ statsL)
{
    __shared__ float cs[128];
    __shared__ float cq[128];
    const int tid = threadIdx.x;
    const int row0 = blockIdx.x * 64;
    if (tid < 128) { cs[tid] = 0.f; cq[tid] = 0.f; }
    __syncthreads();

    MM_CORE_G(Ah, Wth)

    float b2v[4];
    #pragma unroll
    for (int t = 0; t < 4; ++t) b2v[t] = b2[64 * wc + 16 * t + ml];
    float st[4] = {0.f, 0.f, 0.f, 0.f};
    float qt[4] = {0.f, 0.f, 0.f, 0.f};
    #pragma unroll
    for (int r = 0; r < 2; ++r)
        #pragma unroll
        for (int j = 0; j < 4; ++j) {
            int grow = row0 + 32 * wr + 16 * r + quad * 4 + j;
            if (grow < NN) {
                #pragma unroll
                for (int t = 0; t < 4; ++t) {
                    int gcol = 64 * wc + 16 * t + ml;
                    float v = fmaxf(acc[r][t][j] + b2v[t], 0.f);
                    Oh[(size_t)grow * 128 + gcol] = (_Float16)v;
                    st[t] += v;
                    qt[t] += v * v;
                }
            }
        }
    #pragma unroll
    for (int t = 0; t < 4; ++t) {
        int gcol = 64 * wc + 16 * t + ml;
        atomicAdd(&cs[gcol], st[t]);
        atomicAdd(&cq[gcol], qt[t]);
    }
    __syncthreads();
    if (tid < 128) {
        float* bank = statsL + (blockIdx.x & (SBANK - 1)) * 256;
        atomicAdd(&bank[tid], cs[tid]);
        atomicAdd(&bank[128 + tid], cq[tid]);
    }
}

// ---------------------------------------------------------------------------
// gather-aggregate: 16 lanes/node, half8 loads, 8-edge unroll
// ---------------------------------------------------------------------------

__global__ __launch_bounds__(256) void k_aggregate(
    const _Float16* __restrict__ Ph, const int* __restrict__ row_start,
    const int* __restrict__ ssrc, const float* __restrict__ b1,
    const float* __restrict__ cvec, _Float16* __restrict__ Mh)
{
    int idx = blockIdx.x * 256 + threadIdx.x;
    int node = idx >> 4, q = idx & 15;
    if (node >= NN) return;
    int s0 = row_start[node], s1 = row_start[node + 1];
    float degp1 = (float)(s1 - s0 + 1);
    float acc[8];
    half8 pv = *(const half8*)&Ph[(size_t)node * 128 + q * 8];
    #pragma unroll
    for (int j = 0; j < 8; ++j)
        acc[j] = (float)pv[j] + fmaf(degp1, cvec[q * 8 + j], b1[q * 8 + j]);
    int e = s0;
    for (; e + 7 < s1; e += 8) {
        int sidx[8];
        #pragma unroll
        for (int u = 0; u < 8; ++u)
            sidx[u] = __builtin_nontemporal_load(&ssrc[e + u]);
        half8 v[8];
        #pragma unroll
        for (int u = 0; u < 8; ++u)
            v[u] = *(const half8*)&Ph[(size_t)sidx[u] * 128 + q * 8];
        #pragma unroll
        for (int j = 0; j < 8; ++j)
            acc[j] += (((float)v[0][j] + (float)v[1][j]) + ((float)v[2][j] + (float)v[3][j]))
                    + (((float)v[4][j] + (float)v[5][j]) + ((float)v[6][j] + (float)v[7][j]));
    }
    for (; e + 1 < s1; e += 2) {
        int sa = __builtin_nontemporal_load(&ssrc[e]);
        int sb = __builtin_nontemporal_load(&ssrc[e + 1]);
        half8 va = *(const half8*)&Ph[(size_t)sa * 128 + q * 8];
        half8 vb = *(const half8*)&Ph[(size_t)sb * 128 + q * 8];
        #pragma unroll
        for (int j = 0; j < 8; ++j) acc[j] += (float)va[j] + (float)vb[j];
    }
    if (e < s1) {
        int sa = __builtin_nontemporal_load(&ssrc[e]);
        half8 va = *(const half8*)&Ph[(size_t)sa * 128 + q * 8];
        #pragma unroll
        for (int j = 0; j < 8; ++j) acc[j] += (float)va[j];
    }
    half8 o;
    #pragma unroll
    for (int j = 0; j < 8; ++j) o[j] = (_Float16)fmaxf(acc[j], 0.f);
    __builtin_nontemporal_store(o, (half8*)&Mh[(size_t)node * 128 + q * 8]);
}

// ---------------------------------------------------------------------------
// mean-pool per graph (BN sc/sh inline from 8-bank stats)
// ---------------------------------------------------------------------------

__global__ __launch_bounds__(128) void k_pool(
    const _Float16* __restrict__ Ah, const int* __restrict__ batch,
    const float* __restrict__ statsL,
    const float* __restrict__ g_, const float* __restrict__ be,
    float* __restrict__ pooled, int loff)
{
    __shared__ float red[8][128];
    int g = blockIdx.x;
    int t = threadIdx.x;
    int rg = t >> 4, seg = t & 15;
    int lo = 0, hi = NN;
    while (lo < hi) { int mid = (lo + hi) >> 1; if (batch[mid] < g) lo = mid + 1; else hi = mid; }
    int s = lo;
    lo = s; hi = NN;
    while (lo < hi) { int mid = (lo + hi) >> 1; if (batch[mid] < g + 1) lo = mid + 1; else hi = mid; }
    int e = lo;
    float acc[8] = {};
    for (int i = s + rg; i < e; i += 8) {
        half8 v = *(const half8*)&Ah[(size_t)i * 128 + seg * 8];
        #pragma unroll
        for (int j = 0; j < 8; ++j) acc[j] += (float)v[j];
    }
    #pragma unroll
    for (int j = 0; j < 8; ++j) red[rg][seg * 8 + j] = acc[j];
    __syncthreads();
    int cnt = e - s;
    float inv = 1.0f / (float)(cnt > 0 ? cnt : 1);
    if (t < 128) {
        float s_ = 0.f;
        #pragma unroll
        for (int r = 0; r < 8; ++r) s_ += red[r][t];
        float sc, sh;
        bn_sc_sh(statsL, g_, be, t, sc, sh);
        pooled[g * 384 + loff + t] = fmaf(sc, s_ * inv, sh);
    }
}

__global__ __launch_bounds__(128) void k_final(
    const float* __restrict__ pooled,
    const float* __restrict__ Wl1, const float* __restrict__ bl1,
    const float* __restrict__ Wl2, const float* __restrict__ bl2,
    float* __restrict__ out)
{
    __shared__ float pr[384];
    __shared__ float red[128];
    int g = blockIdx.x, j = threadIdx.x;
    for (int i = j; i < 384; i += 128) pr[i] = pooled[g * 384 + i];
    __syncthreads();
    float acc = bl1[j];
    for (int k = 0; k < 384; ++k) acc = fmaf(pr[k], Wl1[k * 128 + j], acc);
    float r = fmaxf(acc, 0.f) * Wl2[j];
    red[j] = r;
    __syncthreads();
    for (int off = 64; off > 0; off >>= 1) {
        if (j < off) red[j] += red[j + off];
        __syncthreads();
    }
    if (j == 0) out[g] = red[0] + bl2[0];
}

extern "C" void kernel_launch(void* const* d_in, const int* in_sizes, int n_in,
                              void* d_out, int out_size, void* d_ws, size_t ws_size,
                              hipStream_t stream)
{
    const float* x     = (const float*)d_in[0];
    const int*   z     = (const int*)d_in[1];
    const int*   ei    = (const int*)d_in[2];
    const int*   batch = (const int*)d_in[3];
    const float* W1a[3] = {(const float*)d_in[4],  (const float*)d_in[10], (const float*)d_in[16]};
    const float* b1a[3] = {(const float*)d_in[5],  (const float*)d_in[11], (const float*)d_in[17]};
    const float* W2a[3] = {(const float*)d_in[6],  (const float*)d_in[12], (const float*)d_in[18]};
    const float* b2a[3] = {(const float*)d_in[7],  (const float*)d_in[13], (const float*)d_in[19]};
    const float* ga[3]  = {(const float*)d_in[8],  (const float*)d_in[14], (const float*)d_in[20]};
    const float* bea[3] = {(const float*)d_in[9],  (const float*)d_in[15], (const float*)d_in[21]};
    const float* Wl1 = (const float*)d_in[22];
    const float* bl1 = (const float*)d_in[23];
    const float* Wl2 = (const float*)d_in[24];
    const float* bl2 = (const float*)d_in[25];
    float* out = (float*)d_out;

    char* ws = (char*)d_ws;
    size_t off = 0;
    auto alloc = [&](size_t bytes) {
        void* p = ws + off;
        off += (bytes + 255) & ~(size_t)255;
        return p;
    };
    _Float16* Xh  = (_Float16*)alloc((size_t)NROWS_PAD * 128 * 2);
    _Float16* Ph  = (_Float16*)alloc((size_t)NROWS_PAD * 128 * 2);
    _Float16* Mh  = (_Float16*)alloc((size_t)NROWS_PAD * 128 * 2);
    _Float16* Ahb = (_Float16*)alloc((size_t)NROWS_PAD * 128 * 2);
    _Float16* Wt1 = (_Float16*)alloc((size_t)128 * 128 * 2);
    _Float16* Wt2 = (_Float16*)alloc((size_t)128 * 128 * 2);
    int*   ebuf     = (int*)alloc((size_t)EE * 4);
    int*   ssrc     = (int*)alloc((size_t)EE * 4);
    int*   row_st   = (int*)alloc((size_t)(NN + 1) * 4);
    int*   bcount   = (int*)alloc((size_t)NB * 4);
    int*   bstart   = (int*)alloc((size_t)(NB + 1) * 4);
    int*   bcursor  = (int*)alloc((size_t)NB * 4);
    float* cvec     = (float*)alloc(128 * 4);
    float* stats    = (float*)alloc((size_t)3 * SBANK * 256 * 4);  // [3][8][colsum|colsq]
    float* pooled   = (float*)alloc((size_t)GG * 384 * 4);

    const int gemmBlocks = (NN + 63) / 64;           // 1563
    const int aggBlocks  = (NN * 16 + 255) / 256;    // 6250

    // ---- one-time per call ----
    hipMemsetAsync(stats, 0, (size_t)3 * SBANK * 256 * 4, stream);
    hipMemsetAsync(bcount, 0, (size_t)NB * 4, stream);
    k_xcast<<<(NN * 128 / 8 + 255) / 256, 256, 0, stream>>>(x, Xh);
    k_bhist<<<PBLOCKS, 256, 0, stream>>>(ei, bcount);
    k_bscan<<<1, 512, 0, stream>>>(bcount, bstart, bcursor, row_st);
    k_part<<<PBLOCKS, 256, 0, stream>>>(ei, bcursor, ebuf);
    k_csrbucket<<<NB, 256, 0, stream>>>(ebuf, bstart, row_st, ssrc);

    for (int l = 0; l < 3; ++l) {
        float* statsL   = stats + (size_t)l * SBANK * 256;
        const float* statsPrev = (l > 0) ? stats + (size_t)(l - 1) * SBANK * 256 : stats;
        const float* pg   = (l > 0) ? ga[l - 1] : ga[0];
        const float* pbe  = (l > 0) ? bea[l - 1] : bea[0];
        k_prep<<<129, 256, 0, stream>>>(W1a[l], W2a[l], statsPrev, pg, pbe,
                                        Wt1, Wt2, cvec, l);
        if (l == 0)
            k_mm_embed<<<gemmBlocks, 256, 0, stream>>>(Xh, Wt1, z, W1a[0], Ph);
        else
            k_mm1<<<gemmBlocks, 256, 0, stream>>>(Ahb, Wt1, Ph);
        k_aggregate<<<aggBlocks, 256, 0, stream>>>(Ph, row_st, ssrc, b1a[l], cvec, Mh);
        k_mm2<<<gemmBlocks, 256, 0, stream>>>(Mh, Wt2, b2a[l], Ahb, statsL);
        k_pool<<<GG, 128, 0, stream>>>(Ahb, batch, statsL, ga[l], bea[l],
                                       pooled, l * 128);
    }
    k_final<<<GG, 128, 0, stream>>>(pooled, Wl1, bl1, Wl2, bl2, out);
}